// Round 1
// baseline (805.241 us; speedup 1.0000x reference)
//
#include <hip/hip_runtime.h>
#include <cstdint>
#include <cstddef>

#define B_  256
#define T_  128
#define NS_ 12
#define NC_ 4
#define M_  6

constexpr float MU_F      = 0.1f;
constexpr float REG_FAC_F = (float)(1.6 * 1.6 - 1.0);   // 1.56000000000000005 -> f32

// ---- staging buffer layout (float offsets) ----
#define OF_FX   0
#define OF_FU   144
#define OF_FXX  192
#define OF_FXU  1920
#define OF_FUU  2496
#define OF_QXX  2688
#define OF_QXU  2832
#define OF_QUU  2880
#define OF_QX   2896
#define OF_QU   2908
#define OF_CX   2912
#define OF_CU   2984
#define OF_C    3008
#define OF_S    3014
#define STG_N   3020

// ---- output layout (float offsets into d_out) ----
// ku (B,T,4) | Ku (B,T,4,12) | ks (B,T,6) | Ks (B,T,6,12) | dV (B,2) | opterr | Vx (B,12) | Vxx (B,12,12)
#define O_KU    0
#define O_KUBIG 131072
#define O_KS    1703936
#define O_KSBIG 1900544
#define O_DV    4259840
#define O_OPT   4260352
#define O_VX    4260353
#define O_VXX   4263425

// LDS-only barrier: drain LDS ops, sync waves, but leave global_load_lds (vmcnt) in flight.
__device__ __forceinline__ void bar_lds() {
    asm volatile("s_waitcnt lgkmcnt(0)\n\ts_barrier" ::: "memory");
}

__device__ __forceinline__ void gl_lds16(const float* g, float* l) {
    __builtin_amdgcn_global_load_lds((const __attribute__((address_space(1))) void*)g,
                                     (__attribute__((address_space(3))) void*)l, 16, 0, 0);
}
__device__ __forceinline__ void gl_lds4(const float* g, float* l) {
    __builtin_amdgcn_global_load_lds((const __attribute__((address_space(1))) void*)g,
                                     (__attribute__((address_space(3))) void*)l, 4, 0, 0);
}

__global__ __launch_bounds__(256) void ddp_backward(
    const float* __restrict__ qx,  const float* __restrict__ qu,
    const float* __restrict__ qxx, const float* __restrict__ qxu,
    const float* __restrict__ quu, const float* __restrict__ fx,
    const float* __restrict__ fu,  const float* __restrict__ fxx,
    const float* __restrict__ fxu, const float* __restrict__ fuu,
    const float* __restrict__ cx,  const float* __restrict__ cu,
    const float* __restrict__ c_,  const float* __restrict__ s_,
    const float* __restrict__ px,  const float* __restrict__ pxx,
    float* __restrict__ out, float* __restrict__ ws)
{
    const int tid  = threadIdx.x;
    const int b    = blockIdx.x;
    const int lane = tid & 63;
    const int wv   = tid >> 6;

    __shared__ float stg[2][STG_N];
    __shared__ float sVx[12], sVxx[144];
    __shared__ float sfxV[144], sfuV[48];
    __shared__ float sQxx[144], sQxu[48];
    __shared__ float sQuuR[16], sQuu2[16], sM4[16];
    __shared__ float stQux[48];
    __shared__ float sQxb[12], sQub[4], sQu[4], sQx2[12];
    __shared__ float sr[6], scinv[6], ssc[6];
    __shared__ float sKu[48], sku[4], sKtQ[48];
    __shared__ float sAcc[4];   // dV0, dV1, quErr, muErr

    const float* srcs[14] = {qx, qu, qxx, qxu, quu, fx, fu, fxx, fxu, fuu, cx, cu, c_, s_};

    auto prefetch = [&](float* dst, int tt) {
        const size_t bt = (size_t)b * T_ + tt;
        constexpr int ch_arr[22]  = {5,6,7,7,7,7,7,7,7,8,8,8,9,2,3,4,0,1,10,11,12,13};
        constexpr int ch_goff[22] = {0,0,0,256,512,768,1024,1280,1536,0,256,512,0,0,0,0,0,0,0,0,0,0};
        constexpr int ch_loff[22] = {OF_FX, OF_FU,
                                     OF_FXX, OF_FXX+256, OF_FXX+512, OF_FXX+768,
                                     OF_FXX+1024, OF_FXX+1280, OF_FXX+1536,
                                     OF_FXU, OF_FXU+256, OF_FXU+512,
                                     OF_FUU, OF_QXX, OF_QXU, OF_QUU, OF_QX, OF_QU,
                                     OF_CX, OF_CU, OF_C, OF_S};
        constexpr int ch_nb[22]   = {576,192,1024,1024,1024,1024,1024,1024,768,
                                     1024,1024,256,768,576,192,64,48,16,288,96,24,24};
        constexpr int sl[14]      = {12,4,144,48,16,144,48,1728,576,192,72,24,6,6};
        #pragma unroll
        for (int ci = 0; ci < 22; ++ci) {
            if ((ci & 3) == wv) {
                const float* g = srcs[ch_arr[ci]] + bt * (size_t)sl[ch_arr[ci]] + ch_goff[ci];
                float* l = dst + ch_loff[ci];
                if ((ch_nb[ci] & 15) == 0) {
                    if (lane * 16 < ch_nb[ci]) gl_lds16(g + lane * 4, l);
                } else {
                    if (lane * 4  < ch_nb[ci]) gl_lds4 (g + lane,     l);
                }
            }
        }
    };

    // ---------- prologue ----------
    if (tid < 144) sVxx[tid] = pxx[(size_t)b * 144 + tid];
    if (tid < 12)  sVx[tid]  = px[(size_t)b * 12 + tid];
    if (tid == 0)  { sAcc[0] = 0.f; sAcc[1] = 0.f; sAcc[2] = 0.f; sAcc[3] = 0.f; }
    prefetch(stg[0], T_ - 1);
    __syncthreads();   // full drain: staging for t=T-1 complete

    int cur = 0;
    for (int t = T_ - 1; t >= 0; --t) {
        const float* S = stg[cur];
        if (t > 0) prefetch(stg[cur ^ 1], t - 1);
        const size_t bt = (size_t)b * T_ + t;

        // ---------- P1: fxV, fuV + small precomputes ----------
        if (tid < 144) {
            const int i = tid / 12, k = tid % 12;
            float acc = 0.f;
            #pragma unroll
            for (int m = 0; m < 12; ++m) acc += S[OF_FX + m*12 + i] * sVxx[m*12 + k];
            sfxV[tid] = acc;
        } else if (tid < 192) {
            const int idx = tid - 144, a = idx / 12, k = idx % 12;
            float acc = 0.f;
            #pragma unroll
            for (int m = 0; m < 12; ++m) acc += S[OF_FU + m*4 + a] * sVxx[m*12 + k];
            sfuV[idx] = acc;
        } else if (tid < 198) {
            const int k = tid - 192;
            const float cc = S[OF_C + k], ssv = S[OF_S + k];
            sr[k] = ssv * cc + MU_F;
            scinv[k] = 1.0f / cc;
            ssc[k] = ssv / cc;
        } else if (tid < 210) {
            const int i = tid - 198;
            float acc = S[OF_QX + i];
            #pragma unroll
            for (int k = 0; k < 6; ++k)  acc += S[OF_CX + k*12 + i] * S[OF_S + k];
            #pragma unroll
            for (int m = 0; m < 12; ++m) acc += S[OF_FX + m*12 + i] * sVx[m];
            sQxb[i] = acc;
        } else if (tid < 214) {
            const int a = tid - 210;
            float acc = S[OF_QU + a];
            #pragma unroll
            for (int k = 0; k < 6; ++k)  acc += S[OF_CU + k*4 + a] * S[OF_S + k];
            #pragma unroll
            for (int m = 0; m < 12; ++m) acc += S[OF_FU + m*4 + a] * sVx[m];
            sQub[a] = acc;
        }
        bar_lds();

        // ---------- P2: Qxx, Qxu, QuuRaw ----------
        if (tid < 144) {
            const int i = tid / 12, j = tid % 12; (void)j;
            float acc = S[OF_QXX + tid];
            #pragma unroll
            for (int k = 0; k < 12; ++k) acc += sfxV[i*12 + k] * S[OF_FX + k*12 + (tid % 12)];
            #pragma unroll
            for (int ss2 = 0; ss2 < 12; ++ss2) acc += sVx[ss2] * S[OF_FXX + ss2*144 + tid];
            sQxx[tid] = acc;
        } else if (tid < 192) {
            const int idx = tid - 144, i = idx / 4, j = idx % 4;
            float acc = S[OF_QXU + idx];
            #pragma unroll
            for (int k = 0; k < 12; ++k) acc += sfxV[i*12 + k] * S[OF_FU + k*4 + j];
            #pragma unroll
            for (int ss2 = 0; ss2 < 12; ++ss2) acc += sVx[ss2] * S[OF_FXU + ss2*48 + idx];
            sQxu[idx] = acc;
        } else if (tid < 208) {
            const int idx = tid - 192, a = idx / 4, b2 = idx % 4;
            float acc = S[OF_QUU + idx];
            #pragma unroll
            for (int k = 0; k < 12; ++k) acc += sfuV[a*12 + k] * S[OF_FU + k*4 + b2];
            #pragma unroll
            for (int ss2 = 0; ss2 < 12; ++ss2) acc += sVx[ss2] * S[OF_FUU + ss2*16 + idx];
            sQuuR[idx] = acc;
        }
        bar_lds();

        // ---------- P3: constraint-corrected quantities ----------
        if (tid < 144) {
            const int i = tid / 12, j = tid % 12;
            float acc = sQxx[tid];
            #pragma unroll
            for (int k = 0; k < 6; ++k) acc -= S[OF_CX + k*12 + i] * ssc[k] * S[OF_CX + k*12 + j];
            sQxx[tid] = acc;                                    // Qxx2 in place
        } else if (tid < 192) {
            const int idx = tid - 144, a = idx / 12, i = idx % 12;
            float acc = sQxu[i*4 + a];
            #pragma unroll
            for (int k = 0; k < 6; ++k) acc -= S[OF_CU + k*4 + a] * ssc[k] * S[OF_CX + k*12 + i];
            stQux[idx] = acc;                                   // tempQux[a][i]
        } else if (tid < 208) {
            const int idx = tid - 192, a = idx / 4, b2 = idx % 4;
            const float q = 0.5f * (sQuuR[idx] + sQuuR[b2*4 + a]);
            float cs = 0.f;
            #pragma unroll
            for (int k = 0; k < 6; ++k) cs += ssc[k] * S[OF_CU + k*4 + a] * S[OF_CU + k*4 + b2];
            const float q2 = q - cs;
            sQuu2[idx] = q2;                                    // Quu - cuSCcu
            sM4[idx]   = q2 + S[OF_QUU + idx] * REG_FAC_F;      // Quu_reg - cuSCcu
        } else if (tid < 212) {
            const int a = tid - 208;
            float acc = sQub[a];
            #pragma unroll
            for (int k = 0; k < 6; ++k) acc -= S[OF_CU + k*4 + a] * scinv[k] * sr[k];
            sQu[a] = acc;                                       // final Qu
        } else if (tid < 224) {
            const int i = tid - 212;
            float acc = sQxb[i];
            #pragma unroll
            for (int k = 0; k < 6; ++k) acc -= S[OF_CX + k*12 + i] * scinv[k] * sr[k];
            sQx2[i] = acc;
        }
        bar_lds();

        // ---------- P4: 4x4 solve (unpivoted LU, redundant per lane), 13 RHS columns ----------
        if (tid < 13) {
            float a00=sM4[0],  a01=sM4[1],  a02=sM4[2],  a03=sM4[3];
            float a10=sM4[4],  a11=sM4[5],  a12=sM4[6],  a13=sM4[7];
            float a20=sM4[8],  a21=sM4[9],  a22=sM4[10], a23=sM4[11];
            float a30=sM4[12], a31=sM4[13], a32=sM4[14], a33=sM4[15];
            const float i0 = 1.0f / a00;
            const float l10 = a10*i0, l20 = a20*i0, l30 = a30*i0;
            a11 -= l10*a01; a12 -= l10*a02; a13 -= l10*a03;
            a21 -= l20*a01; a22 -= l20*a02; a23 -= l20*a03;
            a31 -= l30*a01; a32 -= l30*a02; a33 -= l30*a03;
            const float i1 = 1.0f / a11;
            const float l21 = a21*i1, l31 = a31*i1;
            a22 -= l21*a12; a23 -= l21*a13;
            a32 -= l31*a12; a33 -= l31*a13;
            const float i2 = 1.0f / a22;
            const float l32 = a32*i2;
            a33 -= l32*a23;

            float r0, r1, r2, r3;
            if (tid == 0) { r0 = sQu[0]; r1 = sQu[1]; r2 = sQu[2]; r3 = sQu[3]; }
            else { const int i = tid - 1; r0 = stQux[i]; r1 = stQux[12+i]; r2 = stQux[24+i]; r3 = stQux[36+i]; }

            const float y0 = r0;
            const float y1 = r1 - l10*y0;
            const float y2 = r2 - l20*y0 - l21*y1;
            const float y3 = r3 - l30*y0 - l31*y1 - l32*y2;
            float x3 = y3 / a33;
            float x2 = (y2 - a23*x3) * i2;
            float x1 = (y1 - a12*x2 - a13*x3) * i1;
            float x0 = (y0 - a01*x1 - a02*x2 - a03*x3) * i0;
            x0 = -x0; x1 = -x1; x2 = -x2; x3 = -x3;

            if (tid == 0) {
                sku[0]=x0; sku[1]=x1; sku[2]=x2; sku[3]=x3;
                float* kg = out + O_KU + bt*4;
                kg[0]=x0; kg[1]=x1; kg[2]=x2; kg[3]=x3;
            } else {
                const int i = tid - 1;
                sKu[i]=x0; sKu[12+i]=x1; sKu[24+i]=x2; sKu[36+i]=x3;
                float* Kg = out + O_KUBIG + bt*48;
                Kg[i]=x0; Kg[12+i]=x1; Kg[24+i]=x2; Kg[36+i]=x3;
            }
        }
        bar_lds();

        // ---------- P5: KtQ, ks, Ks, dV/err accumulators ----------
        if (tid < 48) {
            const int i = tid / 4, a = tid % 4;
            float acc = 0.f;
            #pragma unroll
            for (int b2 = 0; b2 < 4; ++b2) acc += sKu[b2*12 + i] * sQuu2[b2*4 + a];
            sKtQ[tid] = acc;                                    // KtQ[i][a] = (Ku^T Quu2)
        } else if (tid < 54) {
            const int k = tid - 48;
            float cuku = 0.f;
            #pragma unroll
            for (int a = 0; a < 4; ++a) cuku += S[OF_CU + k*4 + a] * sku[a];
            out[O_KS + bt*6 + k] = -scinv[k] * (sr[k] + S[OF_S + k] * cuku);
        } else if (tid < 126) {
            const int idx = tid - 54, k = idx / 12, i = idx % 12;
            float acc = S[OF_CX + k*12 + i];
            #pragma unroll
            for (int a = 0; a < 4; ++a) acc += S[OF_CU + k*4 + a] * sKu[a*12 + i];
            out[O_KSBIG + bt*72 + idx] = -(ssc[k] * acc);
        } else if (tid == 126) {
            float d = 0.f;
            #pragma unroll
            for (int a = 0; a < 4; ++a) d += sku[a] * sQu[a];
            sAcc[0] += d;
        } else if (tid == 127) {
            float d = 0.f;
            #pragma unroll
            for (int a = 0; a < 4; ++a)
                #pragma unroll
                for (int b2 = 0; b2 < 4; ++b2) d += sku[a] * sQuu2[a*4 + b2] * sku[b2];
            sAcc[1] += 0.5f * d;
        } else if (tid == 128) {
            float m = 0.f;
            #pragma unroll
            for (int a = 0; a < 4; ++a) m = fmaxf(m, fabsf(sQu[a]));
            sAcc[2] = fmaxf(sAcc[2], m);
        } else if (tid == 129) {
            float m = 0.f;
            #pragma unroll
            for (int k = 0; k < 6; ++k) m = fmaxf(m, fabsf(sr[k]));
            sAcc[3] = fmaxf(sAcc[3], m);
        }
        bar_lds();

        // ---------- P6: Vxx_new (symmetrized), Vx_new ----------
        if (tid < 144) {
            const int i = tid / 12, j = tid % 12;
            const float v1 = sQxx[i*12 + j], v2 = sQxx[j*12 + i];  // Qxx2
            float qk = 0.f, kk1 = 0.f, kk2 = 0.f;
            #pragma unroll
            for (int a = 0; a < 4; ++a) {
                const float kui = sKu[a*12 + i], kuj = sKu[a*12 + j];
                qk  += stQux[a*12 + i] * kuj + stQux[a*12 + j] * kui;  // QxuKu[i][j]+QxuKu[j][i]
                kk1 += sKtQ[i*4 + a] * kuj;
                kk2 += sKtQ[j*4 + a] * kui;
            }
            sVxx[tid] = 0.5f * (v1 + v2) + qk + 0.5f * (kk1 + kk2);
        } else if (tid < 156) {
            const int i = tid - 144;
            float acc = sQx2[i];
            #pragma unroll
            for (int a = 0; a < 4; ++a)
                acc += sKu[a*12 + i] * sQu[a] + sKtQ[i*4 + a] * sku[a] + stQux[a*12 + i] * sku[a];
            sVx[i] = acc;
        }
        __syncthreads();   // full drain: prefetch for t-1 complete + carry updated
        cur ^= 1;
    }

    // ---------- epilogue ----------
    if (tid == 0) {
        out[O_DV + b*2 + 0] = sAcc[0];
        out[O_DV + b*2 + 1] = sAcc[1];
        ws[b] = fmaxf(sAcc[2], sAcc[3]);
    }
    if (tid < 12)  out[O_VX + b*12 + tid] = sVx[tid];
    if (tid < 144) out[O_VXX + (size_t)b*144 + tid] = sVxx[tid];
}

__global__ __launch_bounds__(256) void opt_reduce(const float* __restrict__ ws,
                                                  float* __restrict__ out)
{
    float v = ws[threadIdx.x];
    #pragma unroll
    for (int o = 32; o > 0; o >>= 1) v = fmaxf(v, __shfl_down(v, o, 64));
    __shared__ float m[4];
    if ((threadIdx.x & 63) == 0) m[threadIdx.x >> 6] = v;
    __syncthreads();
    if (threadIdx.x == 0) out[O_OPT] = fmaxf(fmaxf(m[0], m[1]), fmaxf(m[2], m[3]));
}

extern "C" void kernel_launch(void* const* d_in, const int* in_sizes, int n_in,
                              void* d_out, int out_size, void* d_ws, size_t ws_size,
                              hipStream_t stream) {
    const float* qx  = (const float*)d_in[0];
    const float* qu  = (const float*)d_in[1];
    const float* qxx = (const float*)d_in[2];
    const float* qxu = (const float*)d_in[3];
    const float* quu = (const float*)d_in[4];
    const float* fx  = (const float*)d_in[5];
    const float* fu  = (const float*)d_in[6];
    const float* fxx = (const float*)d_in[7];
    const float* fxu = (const float*)d_in[8];
    const float* fuu = (const float*)d_in[9];
    const float* cx  = (const float*)d_in[10];
    const float* cu  = (const float*)d_in[11];
    const float* c_  = (const float*)d_in[12];
    const float* s_  = (const float*)d_in[13];
    const float* px  = (const float*)d_in[14];
    const float* pxx = (const float*)d_in[15];
    float* out = (float*)d_out;
    float* ws  = (float*)d_ws;

    hipLaunchKernelGGL(ddp_backward, dim3(B_), dim3(256), 0, stream,
                       qx, qu, qxx, qxu, quu, fx, fu, fxx, fxu, fuu,
                       cx, cu, c_, s_, px, pxx, out, ws);
    hipLaunchKernelGGL(opt_reduce, dim3(1), dim3(256), 0, stream, ws, out);
}